// Round 8
// baseline (490.135 us; speedup 1.0000x reference)
//
#include <hip/hip_runtime.h>

typedef __attribute__((ext_vector_type(8))) short short8;
typedef __attribute__((ext_vector_type(4))) short short4v;
typedef __attribute__((ext_vector_type(4))) float f32x4;

__device__ __forceinline__ short f2bf(float x) {
    union { float f; unsigned u; } c; c.f = x;
    unsigned u = c.u;
    u += 0x7fffu + ((u >> 16) & 1u);
    return (short)(u >> 16);
}

// ---------------------------------------------------------------------------
// fp32 -> bf16 bulk convert for vis_tokens
__global__ __launch_bounds__(256) void cvt_bf16(const float* __restrict__ s, short* __restrict__ d, int n4) {
    int i = blockIdx.x * 256 + threadIdx.x;
    if (i < n4) {
        float4 v = ((const float4*)s)[i];
        short4 o;
        o.x = f2bf(v.x); o.y = f2bf(v.y); o.z = f2bf(v.z); o.w = f2bf(v.w);
        ((short4*)d)[i] = o;
    }
}

// combined small converts (float4 counts): emb_w 32768, k_w 16384, v_w 16384
__global__ __launch_bounds__(256) void cvt3(const float* __restrict__ emb, const float* __restrict__ kw,
                                            const float* __restrict__ vw,
                                            short* __restrict__ de, short* __restrict__ dk, short* __restrict__ dv) {
    int i = blockIdx.x * 256 + threadIdx.x;   // 0..65535
    const float* s; short* d; int off;
    if (i < 32768) { s = emb; d = de; off = i; }
    else if (i < 49152) { s = kw; d = dk; off = i - 32768; }
    else { s = vw; d = dv; off = i - 49152; }
    float4 v = ((const float4*)s)[off];
    short4 o;
    o.x = f2bf(v.x); o.y = f2bf(v.y); o.z = f2bf(v.z); o.w = f2bf(v.w);
    ((short4*)d)[off] = o;
}

// ---------------------------------------------------------------------------
// Fold conv into W_fold^T; blockIdx.y selects side.
__global__ void build_wfold(const float* __restrict__ cl, const float* __restrict__ cr,
                            float* __restrict__ wfT) {
    const float* conv_w = blockIdx.y ? cr : cl;
    float* o = wfT + (long)blockIdx.y * 327680;
    const int j = blockIdx.x;
    const int ci = threadIdx.x;
    float acc[5] = {0.f, 0.f, 0.f, 0.f, 0.f};
#pragma unroll
    for (int i = 0; i < 5; ++i) {
        int flat = i * 256 + j;
        int c = flat / 5;
        int s = flat % 5;
#pragma unroll
        for (int k = 0; k < 3; ++k) {
            int si = s + k - 1;
            if (si >= 0 && si < 5) acc[si] += conv_w[(c * 256 + ci) * 3 + k];
        }
    }
#pragma unroll
    for (int si = 0; si < 5; ++si)
        o[(si * 256 + ci) * 256 + j] = acc[si] * 0.2f;
}

// ---------------------------------------------------------------------------
// fp32 tiled GEMM (small P-build path): C[row,col]=sum A[row,k]W[col,k]
template <bool BIAS>
__global__ __launch_bounds__(256) void gemm64(const float* __restrict__ A,
                                              const float* __restrict__ W,
                                              const float* __restrict__ bias,
                                              float* __restrict__ C,
                                              int K, int ldC,
                                              long sliceA, long sliceW, long sliceC) {
    A += (long)blockIdx.z * sliceA;
    W += (long)blockIdx.z * sliceW;
    C += (long)blockIdx.z * sliceC;
    const int row0 = blockIdx.x * 64;
    const int col0 = blockIdx.y * 64;
    __shared__ float As[32][68];
    __shared__ float Ws[32][68];
    const int t = threadIdx.x;
    const int tx = t & 15;
    const int ty = t >> 4;
    float acc[4][4] = {};
    for (int kk = 0; kk < K; kk += 32) {
#pragma unroll
        for (int e = 0; e < 8; ++e) {
            int f = t + 256 * e;
            int r = f >> 5, kc = f & 31;
            As[kc][r] = A[(long)(row0 + r) * K + kk + kc];
            Ws[kc][r] = W[(long)(col0 + r) * K + kk + kc];
        }
        __syncthreads();
#pragma unroll
        for (int kc = 0; kc < 32; ++kc) {
            float4 a4 = *(const float4*)&As[kc][ty * 4];
            float4 w4 = *(const float4*)&Ws[kc][tx * 4];
            float av[4] = {a4.x, a4.y, a4.z, a4.w};
            float wv[4] = {w4.x, w4.y, w4.z, w4.w};
#pragma unroll
            for (int i = 0; i < 4; ++i)
#pragma unroll
                for (int jj = 0; jj < 4; ++jj)
                    acc[i][jj] += av[i] * wv[jj];
        }
        __syncthreads();
    }
#pragma unroll
    for (int r = 0; r < 4; ++r) {
        int row = row0 + ty * 4 + r;
#pragma unroll
        for (int c = 0; c < 4; ++c) {
            int col = col0 + tx * 4 + c;
            float v = acc[r][c];
            if (BIAS) v += bias[col];
            C[(long)row * ldC + col] = v;
        }
    }
}

// ---------------------------------------------------------------------------
// bf16 MFMA GEMM (classifier): C = A.W^T + bias, fp32 out
__global__ __launch_bounds__(256) void gemm_bf(const short* __restrict__ A,
                                               const short* __restrict__ W,
                                               const float* __restrict__ bias,
                                               float* __restrict__ Cf,
                                               int K, int ldC,
                                               long sliceA, long sliceC) {
    A += (long)blockIdx.z * sliceA;
    const int row0 = blockIdx.x * 64, col0 = blockIdx.y * 64;
    __shared__ short As[64 * 40];
    __shared__ short Ws[64 * 40];
    const int t = threadIdx.x;
    const int wid = t >> 6, lane = t & 63, sub = lane & 15, quad = lane >> 4;
    const int wy = wid >> 1, wx = wid & 1;
    const int srow = t >> 2, sseg = t & 3;
    f32x4 acc00 = {0.f, 0.f, 0.f, 0.f}, acc01 = acc00, acc10 = acc00, acc11 = acc00;
    for (int kk = 0; kk < K; kk += 32) {
        *(short8*)&As[srow * 40 + sseg * 8] = *(const short8*)&A[(long)(row0 + srow) * K + kk + sseg * 8];
        *(short8*)&Ws[srow * 40 + sseg * 8] = *(const short8*)&W[(long)(col0 + srow) * K + kk + sseg * 8];
        __syncthreads();
        short8 a0 = *(const short8*)&As[(wy * 32 + sub) * 40 + quad * 8];
        short8 a1 = *(const short8*)&As[(wy * 32 + 16 + sub) * 40 + quad * 8];
        short8 b0 = *(const short8*)&Ws[(wx * 32 + sub) * 40 + quad * 8];
        short8 b1 = *(const short8*)&Ws[(wx * 32 + 16 + sub) * 40 + quad * 8];
        acc00 = __builtin_amdgcn_mfma_f32_16x16x32_bf16(a0, b0, acc00, 0, 0, 0);
        acc01 = __builtin_amdgcn_mfma_f32_16x16x32_bf16(a0, b1, acc01, 0, 0, 0);
        acc10 = __builtin_amdgcn_mfma_f32_16x16x32_bf16(a1, b0, acc10, 0, 0, 0);
        acc11 = __builtin_amdgcn_mfma_f32_16x16x32_bf16(a1, b1, acc11, 0, 0, 0);
        __syncthreads();
    }
    Cf += (long)blockIdx.z * sliceC;
#pragma unroll
    for (int i = 0; i < 2; ++i)
#pragma unroll
        for (int j = 0; j < 2; ++j) {
            f32x4 a = (i == 0) ? (j == 0 ? acc00 : acc01) : (j == 0 ? acc10 : acc11);
#pragma unroll
            for (int r = 0; r < 4; ++r) {
                int row = row0 + wy * 32 + i * 16 + quad * 4 + r;
                int col = col0 + wx * 32 + j * 16 + sub;
                Cf[(long)row * ldC + col] = a[r] + bias[col];
            }
        }
}

// ---------------------------------------------------------------------------
// K/V projection + bias + row LayerNorm fused; V written transposed into Vt.
__global__ __launch_bounds__(256) void gemm_ln(const short* __restrict__ A,
                                               const short* __restrict__ kwbf, const short* __restrict__ vwbf,
                                               const float* __restrict__ k_b, const float* __restrict__ v_b,
                                               const float* __restrict__ gamma, const float* __restrict__ beta,
                                               short* __restrict__ Kout, short* __restrict__ Vt) {
    const bool isV = blockIdx.y != 0;
    const short* W = isV ? vwbf : kwbf;
    const float* bias = isV ? v_b : k_b;
    const int row0 = blockIdx.x * 64;
    __shared__ short As[64 * 40];
    __shared__ short Ws[256 * 40];
    __shared__ float s_mu[64 * 4];
    __shared__ float s_sq[64 * 4];
    __shared__ float s_mv[64 * 2];
    const int t = threadIdx.x;
    const int wid = t >> 6, lane = t & 63, sub = lane & 15, quad = lane >> 4;
    f32x4 acc[4][4];
#pragma unroll
    for (int mi = 0; mi < 4; ++mi)
#pragma unroll
        for (int ni = 0; ni < 4; ++ni) acc[mi][ni] = (f32x4){0.f, 0.f, 0.f, 0.f};

    const int sr = t >> 2, sseg = t & 3;
    for (int kk = 0; kk < 256; kk += 32) {
        *(short8*)&As[sr * 40 + sseg * 8] = *(const short8*)&A[(long)(row0 + sr) * 256 + kk + sseg * 8];
#pragma unroll
        for (int i = 0; i < 4; ++i) {
            int r = i * 64 + sr;
            *(short8*)&Ws[r * 40 + sseg * 8] = *(const short8*)&W[(long)r * 256 + kk + sseg * 8];
        }
        __syncthreads();
        short8 a[4], b[4];
#pragma unroll
        for (int mi = 0; mi < 4; ++mi) a[mi] = *(const short8*)&As[(mi * 16 + sub) * 40 + quad * 8];
#pragma unroll
        for (int ni = 0; ni < 4; ++ni) b[ni] = *(const short8*)&Ws[(wid * 64 + ni * 16 + sub) * 40 + quad * 8];
#pragma unroll
        for (int mi = 0; mi < 4; ++mi)
#pragma unroll
            for (int ni = 0; ni < 4; ++ni)
                acc[mi][ni] = __builtin_amdgcn_mfma_f32_16x16x32_bf16(a[mi], b[ni], acc[mi][ni], 0, 0, 0);
        __syncthreads();
    }
#pragma unroll
    for (int ni = 0; ni < 4; ++ni) {
        float bv = bias[wid * 64 + ni * 16 + sub];
#pragma unroll
        for (int mi = 0; mi < 4; ++mi)
#pragma unroll
            for (int r = 0; r < 4; ++r) acc[mi][ni][r] += bv;
    }
#pragma unroll
    for (int mi = 0; mi < 4; ++mi) {
#pragma unroll
        for (int r = 0; r < 4; ++r) {
            float s = 0.f, q2 = 0.f;
#pragma unroll
            for (int ni = 0; ni < 4; ++ni) {
                float v = acc[mi][ni][r];
                s += v; q2 += v * v;
            }
#pragma unroll
            for (int off = 8; off; off >>= 1) {
                s += __shfl_xor(s, off, 16);
                q2 += __shfl_xor(q2, off, 16);
            }
            if (sub == 0) {
                int row = mi * 16 + quad * 4 + r;
                s_mu[row * 4 + wid] = s;
                s_sq[row * 4 + wid] = q2;
            }
        }
    }
    __syncthreads();
    if (t < 64) {
        float s = s_mu[t * 4] + s_mu[t * 4 + 1] + s_mu[t * 4 + 2] + s_mu[t * 4 + 3];
        float q2 = s_sq[t * 4] + s_sq[t * 4 + 1] + s_sq[t * 4 + 2] + s_sq[t * 4 + 3];
        float mean = s * (1.0f / 256.0f);
        float var = q2 * (1.0f / 256.0f) - mean * mean;
        s_mv[t * 2] = mean;
        s_mv[t * 2 + 1] = rsqrtf(var + 1e-5f);
    }
    __syncthreads();
#pragma unroll
    for (int ni = 0; ni < 4; ++ni) {
        int col = wid * 64 + ni * 16 + sub;
        float g = gamma[col], bb = beta[col];
        if (!isV) {
#pragma unroll
            for (int mi = 0; mi < 4; ++mi)
#pragma unroll
                for (int r = 0; r < 4; ++r) {
                    int row = mi * 16 + quad * 4 + r;
                    float v = (acc[mi][ni][r] - s_mv[row * 2]) * s_mv[row * 2 + 1] * g + bb;
                    Kout[(long)(row0 + row) * 256 + col] = f2bf(v);
                }
        } else {
            int h = col >> 5, dh = col & 31;
#pragma unroll
            for (int mi = 0; mi < 4; ++mi) {
                int rowb = row0 + mi * 16 + quad * 4;
                short4 o;
#pragma unroll
                for (int r = 0; r < 4; ++r) {
                    int row = mi * 16 + quad * 4 + r;
                    float v = (acc[mi][ni][r] - s_mv[row * 2]) * s_mv[row * 2 + 1] * g + bb;
                    ((short*)&o)[r] = f2bf(v);
                }
                int gb = rowb >> 10, n = rowb & 1023;
                *(short4*)&Vt[((long)(gb * 8 + h) * 32 + dh) * 1024 + n] = o;
            }
        }
    }
}

// ---------------------------------------------------------------------------
__global__ void bias_dir_kernel(const float* __restrict__ tp, const float* __restrict__ tpb,
                                const float* __restrict__ dirL, const float* __restrict__ dirR,
                                float* __restrict__ biasL, float* __restrict__ biasR) {
    const float* dir = blockIdx.x ? dirR : dirL;
    float* outp = blockIdx.x ? biasR : biasL;
    __shared__ float sdir[256];
    const int d = threadIdx.x;
    sdir[d] = dir[d];
    __syncthreads();
    float acc = tpb[d];
    for (int j = 0; j < 256; ++j) acc += tp[d * 256 + j] * sdir[j];
    outp[d] = acc;
}

// ---------------------------------------------------------------------------
// Q build, wave-per-row: gather 5 P rows, + dir bias, LN, bf16 out.
__global__ __launch_bounds__(256) void q_build(const int* __restrict__ idsL, const int* __restrict__ idsR,
                                               const float* __restrict__ Pp,
                                               const float* __restrict__ biasL, const float* __restrict__ biasR,
                                               const float* __restrict__ qg, const float* __restrict__ qb,
                                               short* __restrict__ Qbf) {
    const int wid = threadIdx.x >> 6, lane = threadIdx.x & 63;
    const int bl = blockIdx.x * 4 + wid;
    const bool right = blockIdx.y != 0;
    const int* ids = right ? idsR : idsL;
    const float* P = right ? Pp + 655360 : Pp;
    const float* bias = right ? biasR : biasL;
    const int d0 = lane * 4;
    float4 acc = *(const float4*)&bias[d0];
#pragma unroll
    for (int s = 0; s < 5; ++s) {
        int tok = ids[bl * 5 + s];
        float4 p = *(const float4*)&P[(long)(s * 512 + tok) * 256 + d0];
        acc.x += p.x; acc.y += p.y; acc.z += p.z; acc.w += p.w;
    }
    float sum = acc.x + acc.y + acc.z + acc.w;
    float sq = acc.x * acc.x + acc.y * acc.y + acc.z * acc.z + acc.w * acc.w;
#pragma unroll
    for (int off = 32; off; off >>= 1) {
        sum += __shfl_xor(sum, off, 64);
        sq += __shfl_xor(sq, off, 64);
    }
    float mean = sum * (1.0f / 256.0f);
    float var = sq * (1.0f / 256.0f) - mean * mean;
    float rstd = rsqrtf(var + 1e-5f);
    float4 g = *(const float4*)&qg[d0];
    float4 bb = *(const float4*)&qb[d0];
    short4 o;
    o.x = f2bf((acc.x - mean) * rstd * g.x + bb.x);
    o.y = f2bf((acc.y - mean) * rstd * g.y + bb.y);
    o.z = f2bf((acc.z - mean) * rstd * g.z + bb.z);
    o.w = f2bf((acc.w - mean) * rstd * g.w + bb.w);
    *(short4*)&Qbf[(right ? 2097152L : 0L) + (long)bl * 256 + d0] = o;
}

// ---------------------------------------------------------------------------
// Barrier-free, LDS-free MFMA cross-attention with REGISTER DOUBLE-BUFFERING.
// One WAVE per (b, h, 16-l tile), both sides share K/Vt/mask. Per 32-n chunk:
//   scores: two mfma_16x16x32(K-frag, Q-frag) -> S^T tiles
//   p = exp(S*inv*mask); two exp'd C-frags concat == B-frag of K=32 PV MFMA
//   under k-slot->n bijection (j<4 ? 4q+j : 16+4q+j-4); A-frag = 2 short4 Vt loads.
// Next chunk's 8 loads issue before current chunk's compute (latency hiding).
__global__ __launch_bounds__(256, 4) void attn_wave(const short* __restrict__ Qbf,
                                                    const short* __restrict__ Kbf,
                                                    const short* __restrict__ Vt,
                                                    const float* __restrict__ vis_mask,
                                                    const float* __restrict__ tau_p,
                                                    short* __restrict__ Fbf) {
    const int t = threadIdx.x;
    const int wid = t >> 6, lane = t & 63, sub = lane & 15, quad = lane >> 4;
    const int w = blockIdx.x * 4 + wid;   // 0..4095
    const int lt = w & 15;
    const int h = (w >> 4) & 7;
    const int b = w >> 7;
    const int l0 = lt * 16;
    float tau = fminf(fmaxf(tau_p[0], 0.25f), 4.0f);
    const float invscale = 1.0f / (5.656854249492381f * tau);

    const long qoff = (long)(b * 256 + l0 + sub) * 256 + h * 32 + quad * 8;
    const short8 bqL = *(const short8*)&Qbf[qoff];
    const short8 bqR = *(const short8*)&Qbf[2097152 + qoff];

    const short* Kb = Kbf + (long)b * 262144 + h * 32;            // + n*256 + quad*8
    const short* Vb = Vt + (long)(b * 8 + h) * 32768;             // Vt[dh][n]
    const float* mb = vis_mask + (long)(b * 256 + l0 + sub) * 1024 + quad * 4;

    f32x4 oL0 = {0.f, 0.f, 0.f, 0.f}, oL1 = oL0, oR0 = oL0, oR1 = oL0;
    float psL = 0.f, psR = 0.f;

    // ---- prologue: load chunk 0 ----
    short8 ak0 = *(const short8*)&Kb[(long)(0 + sub) * 256 + quad * 8];
    short8 ak1 = *(const short8*)&Kb[(long)(16 + sub) * 256 + quad * 8];
    float4 mk0 = *(const float4*)&mb[0];
    float4 mk1 = *(const float4*)&mb[16];
    short4v v00 = *(const short4v*)&Vb[(long)sub * 1024 + 0 + quad * 4];
    short4v v01 = *(const short4v*)&Vb[(long)sub * 1024 + 16 + quad * 4];
    short4v v10 = *(const short4v*)&Vb[(long)(16 + sub) * 1024 + 0 + quad * 4];
    short4v v11 = *(const short4v*)&Vb[(long)(16 + sub) * 1024 + 16 + quad * 4];

    for (int n0 = 0; n0 < 1024; n0 += 32) {
        // ---- issue next chunk's loads (wrapped so always in-bounds, unconditional) ----
        const int nn = (n0 + 32) & 1023;
        short8 nak0 = *(const short8*)&Kb[(long)(nn + sub) * 256 + quad * 8];
        short8 nak1 = *(const short8*)&Kb[(long)(nn + 16 + sub) * 256 + quad * 8];
        float4 nmk0 = *(const float4*)&mb[nn];
        float4 nmk1 = *(const float4*)&mb[nn + 16];
        short4v nv00 = *(const short4v*)&Vb[(long)sub * 1024 + nn + quad * 4];
        short4v nv01 = *(const short4v*)&Vb[(long)sub * 1024 + nn + 16 + quad * 4];
        short4v nv10 = *(const short4v*)&Vb[(long)(16 + sub) * 1024 + nn + quad * 4];
        short4v nv11 = *(const short4v*)&Vb[(long)(16 + sub) * 1024 + nn + 16 + quad * 4];

        // ---- pack PV A-frags from current V regs ----
        short8 av0, av1;
#pragma unroll
        for (int j = 0; j < 4; ++j) {
            av0[j] = v00[j]; av0[4 + j] = v01[j];
            av1[j] = v10[j]; av1[4 + j] = v11[j];
        }

        // ---- side L ----
        {
            f32x4 c0 = {0.f, 0.f, 0.f, 0.f}, c1 = c0;
            c0 = __builtin_amdgcn_mfma_f32_16x16x32_bf16(ak0, bqL, c0, 0, 0, 0);
            c1 = __builtin_amdgcn_mfma_f32_16x16x32_bf16(ak1, bqL, c1, 0, 0, 0);
            short8 p8;
            float p0 = __expf(c0[0] * invscale * mk0.x);
            float p1 = __expf(c0[1] * invscale * mk0.y);
            float p2 = __expf(c0[2] * invscale * mk0.z);
            float p3 = __expf(c0[3] * invscale * mk0.w);
            float p4 = __expf(c1[0] * invscale * mk1.x);
            float p5 = __expf(c1[1] * invscale * mk1.y);
            float p6 = __expf(c1[2] * invscale * mk1.z);
            float p7 = __expf(c1[3] * invscale * mk1.w);
            psL += ((p0 + p1) + (p2 + p3)) + ((p4 + p5) + (p6 + p7));
            p8[0] = f2bf(p0); p8[1] = f2bf(p1); p8[2] = f2bf(p2); p8[3] = f2bf(p3);
            p8[4] = f2bf(p4); p8[5] = f2bf(p5); p8[6] = f2bf(p6); p8[7] = f2bf(p7);
            oL0 = __builtin_amdgcn_mfma_f32_16x16x32_bf16(av0, p8, oL0, 0, 0, 0);
            oL1 = __builtin_amdgcn_mfma_f32_16x16x32_bf16(av1, p8, oL1, 0, 0, 0);
        }
        // ---- side R ----
        {
            f32x4 c0 = {0.f, 0.f, 0.f, 0.f}, c1 = c0;
            c0 = __builtin_amdgcn_mfma_f32_16x16x32_bf16(ak0, bqR, c0, 0, 0, 0);
            c1 = __builtin_amdgcn_mfma_f32_16x16x32_bf16(ak1, bqR, c1, 0, 0, 0);
            short8 p8;
            float p0 = __expf(c0[0] * invscale * mk0.x);
            float p1 = __expf(c0[1] * invscale * mk0.y);
            float p2 = __expf(c0[2] * invscale * mk0.z);
            float p3 = __expf(c0[3] * invscale * mk0.w);
            float p4 = __expf(c1[0] * invscale * mk1.x);
            float p5 = __expf(c1[1] * invscale * mk1.y);
            float p6 = __expf(c1[2] * invscale * mk1.z);
            float p7 = __expf(c1[3] * invscale * mk1.w);
            psR += ((p0 + p1) + (p2 + p3)) + ((p4 + p5) + (p6 + p7));
            p8[0] = f2bf(p0); p8[1] = f2bf(p1); p8[2] = f2bf(p2); p8[3] = f2bf(p3);
            p8[4] = f2bf(p4); p8[5] = f2bf(p5); p8[6] = f2bf(p6); p8[7] = f2bf(p7);
            oR0 = __builtin_amdgcn_mfma_f32_16x16x32_bf16(av0, p8, oR0, 0, 0, 0);
            oR1 = __builtin_amdgcn_mfma_f32_16x16x32_bf16(av1, p8, oR1, 0, 0, 0);
        }

        // ---- rotate double-buffer ----
        ak0 = nak0; ak1 = nak1; mk0 = nmk0; mk1 = nmk1;
        v00 = nv00; v01 = nv01; v10 = nv10; v11 = nv11;
    }

    // full row-sums for l = sub (combine the 4 quads)
    psL += __shfl_xor(psL, 16, 64); psL += __shfl_xor(psL, 32, 64);
    psR += __shfl_xor(psR, 16, 64); psR += __shfl_xor(psR, 32, 64);
    const float rL = 1.0f / psL, rR = 1.0f / psR;

    // O^T[4*quad+r (+16)][l0+sub] -> F[b,l0+sub][h*32 + 4*quad + r (+16)]
    const long fo = (long)(b * 256 + l0 + sub) * 256 + h * 32 + quad * 4;
    short4v s0, s1;
#pragma unroll
    for (int r = 0; r < 4; ++r) { s0[r] = f2bf(oL0[r] * rL); s1[r] = f2bf(oL1[r] * rL); }
    *(short4v*)&Fbf[fo] = s0;
    *(short4v*)&Fbf[fo + 16] = s1;
#pragma unroll
    for (int r = 0; r < 4; ++r) { s0[r] = f2bf(oR0[r] * rR); s1[r] = f2bf(oR1[r] * rR); }
    *(short4v*)&Fbf[2097152 + fo] = s0;
    *(short4v*)&Fbf[2097152 + fo + 16] = s1;
}

// ---------------------------------------------------------------------------
// Loss: wave per (b,l) pair.
__global__ __launch_bounds__(256) void loss_pair(const float* __restrict__ logits,
                                                 const float* __restrict__ tgt_mask,
                                                 float* __restrict__ accp) {
    const int wid = threadIdx.x >> 6, lane = threadIdx.x & 63;
    const int pid = blockIdx.x * 4 + wid;   // 0..8159
    const int b = pid / 255, l = pid - b * 255;
    const float* ll = logits + (long)(b * 256 + l) * 512;
    const float* lr = logits + 4194304 + (long)(b * 256 + l + 1) * 512;
    float a[8], c[8];
#pragma unroll
    for (int j = 0; j < 8; ++j) {
        a[j] = ll[lane + 64 * j] * 0.5f;
        c[j] = lr[lane + 64 * j] * 0.5f;
    }
    float ml = -1e30f, mr = -1e30f;
#pragma unroll
    for (int j = 0; j < 8; ++j) { ml = fmaxf(ml, a[j]); mr = fmaxf(mr, c[j]); }
#pragma unroll
    for (int off = 32; off; off >>= 1) {
        ml = fmaxf(ml, __shfl_xor(ml, off, 64));
        mr = fmaxf(mr, __shfl_xor(mr, off, 64));
    }
    float sl = 0.f, sr = 0.f;
#pragma unroll
    for (int j = 0; j < 8; ++j) {
        a[j] = __expf(a[j] - ml); sl += a[j];
        c[j] = __expf(c[j] - mr); sr += c[j];
    }
#pragma unroll
    for (int off = 32; off; off >>= 1) {
        sl += __shfl_xor(sl, off, 64);
        sr += __shfl_xor(sr, off, 64);
    }
    float rl = 1.0f / sl, rr = 1.0f / sr;
    float sq = 0.f;
#pragma unroll
    for (int j = 0; j < 8; ++j) {
        float d = a[j] * rl - c[j] * rr;
        sq += d * d;
    }
#pragma unroll
    for (int off = 32; off; off >>= 1) sq += __shfl_xor(sq, off, 64);
    if (lane == 0) atomicAdd(accp, sq * tgt_mask[b * 256 + l]);
}

__global__ __launch_bounds__(256) void loss_final(const float* __restrict__ tgt_mask,
                                                  const float* __restrict__ accp,
                                                  float* __restrict__ outp) {
    const int t = threadIdx.x;
    float s = 0.f;
    for (int i = t; i < 32 * 255; i += 256) {
        int b = i / 255, l = i % 255;
        s += tgt_mask[b * 256 + l];
    }
    __shared__ float red[256];
    red[t] = s;
    __syncthreads();
    for (int st = 128; st; st >>= 1) { if (t < st) red[t] += red[t + st]; __syncthreads(); }
    if (t == 0) outp[0] = 0.1f * accp[0] / fmaxf(red[0], 1.0f);
}

// ---------------------------------------------------------------------------
extern "C" void kernel_launch(void* const* d_in, const int* in_sizes, int n_in,
                              void* d_out, int out_size, void* d_ws, size_t ws_size,
                              hipStream_t stream) {
    const float* vis_tokens = (const float*)d_in[0];
    const int* idsL = (const int*)d_in[1];
    const int* idsR = (const int*)d_in[2];
    const float* tgt_mask = (const float*)d_in[4];
    const float* vis_mask = (const float*)d_in[5];
    const float* emb_w = (const float*)d_in[6];
    const float* dirL = (const float*)d_in[7];
    const float* dirR = (const float*)d_in[8];
    const float* tp_w = (const float*)d_in[9];
    const float* tp_b = (const float*)d_in[10];
    const float* q_g = (const float*)d_in[11];
    const float* q_b = (const float*)d_in[12];
    const float* k_w = (const float*)d_in[13];
    const float* k_b = (const float*)d_in[14];
    const float* v_w = (const float*)d_in[15];
    const float* v_b = (const float*)d_in[16];
    const float* kv_g = (const float*)d_in[17];
    const float* kv_b = (const float*)d_in[18];
    const float* tau = (const float*)d_in[19];
    const float* cls_b = (const float*)d_in[20];
    const float* conv_l = (const float*)d_in[21];
    const float* conv_r = (const float*)d_in[22];
    float* out = (float*)d_out;

    // ---- workspace layout ----
    short* sws = (short*)d_ws;
    short* visbf = sws;                         // 8,388,608
    short* embbf = visbf + 8388608;             // 131,072
    short* kwbf  = embbf + 131072;              // 65,536
    short* vwbf  = kwbf + 65536;                // 65,536
    short* Kbf   = vwbf + 65536;                // 8,388,608
    short* Vt    = Kbf + 8388608;               // 8,388,608
    short* Qbf   = Vt + 8388608;                // 4,194,304 (L|R)
    short* Fbf   = Qbf + 4194304;               // 4,194,304 (L|R)
    float* wfT   = (float*)(Fbf + 4194304);     // 10 slices x 65536
    float* Ms    = wfT + 655360;                // 10 x 65536
    float* Pp    = Ms + 655360;                 // 10 x 131072
    float* bias_l = Pp + 1310720;
    float* bias_r = bias_l + 256;
    float* accp = bias_r + 256;

    (void)hipMemsetAsync(accp, 0, sizeof(float), stream);

    // ---- converts ----
    cvt_bf16<<<8192, 256, 0, stream>>>(vis_tokens, visbf, 2097152);
    cvt3<<<256, 256, 0, stream>>>(emb_w, k_w, v_w, embbf, kwbf, vwbf);

    // ---- ctx path: wfold -> Ms -> P (fp32, small) ----
    build_wfold<<<dim3(256, 2), 256, 0, stream>>>(conv_l, conv_r, wfT);
    gemm64<false><<<dim3(4, 4, 10), 256, 0, stream>>>(tp_w, wfT, nullptr, Ms, 256, 256, 0, 65536, 65536);
    gemm64<false><<<dim3(8, 4, 10), 256, 0, stream>>>(emb_w, Ms, nullptr, Pp, 256, 256, 0, 65536, 131072);
    bias_dir_kernel<<<2, 256, 0, stream>>>(tp_w, tp_b, dirL, dirR, bias_l, bias_r);
    q_build<<<dim3(2048, 2), 256, 0, stream>>>(idsL, idsR, Pp, bias_l, bias_r, q_g, q_b, Qbf);

    // ---- K/V projections + LN fused (V written transposed) ----
    gemm_ln<<<dim3(512, 2), 256, 0, stream>>>(visbf, kwbf, vwbf, k_b, v_b, kv_g, kv_b, Kbf, Vt);

    // ---- barrier-free per-wave MFMA cross-attention (both sides) ----
    attn_wave<<<1024, 256, 0, stream>>>(Qbf, Kbf, Vt, vis_mask, tau, Fbf);

    // ---- tied classifier logits into d_out+1 ----
    gemm_bf<<<dim3(128, 8, 2), 256, 0, stream>>>(Fbf, embbf, cls_b, out + 1, 256, 512,
                                                 2097152, 4194304);

    // ---- SGM agreement loss ----
    loss_pair<<<2040, 256, 0, stream>>>(out + 1, tgt_mask, accp);
    loss_final<<<1, 256, 0, stream>>>(tgt_mask, accp, out);
}